// Round 15
// baseline (50.365 us; speedup 1.0000x reference)
//
#include <hip/hip_runtime.h>
#include <math.h>

#define HH 2048
#define WW 2048
#define T 8
#define NBLK 512

// Gaussian sigma=2, 5 taps, normalized
#define GW0 0.15246914402033867f
#define GW1 0.22184129554377693f
#define GW2 0.25137912086578894f

typedef float f4 __attribute__((ext_vector_type(4)));

struct R8 { float v[8]; };
struct R6 { float v[6]; };
struct Raw { f4 a, b, c; };

__device__ __forceinline__ int reflect_row(int vr) {
    return vr < 0 ? -vr : (vr >= HH ? 2 * HH - 2 - vr : vr);
}

__device__ __forceinline__ Raw load_row3(const float* __restrict__ p, int r, int xb) {
    const float* row = p + (size_t)r * WW;
    Raw o;
    o.a = *(const f4*)(row + max(xb - 4, 0));
    o.b = *(const f4*)(row + xb);
    o.c = *(const f4*)(row + min(xb + 4, WW - 4));
    return o;
}

// horizontal gaussian from raw lab row; output covers x = xb-2 .. xb+5
__device__ __forceinline__ R8 make_h(const Raw& R, bool edgew, bool le, bool re) {
    float w[12] = {R.a.x, R.a.y, R.a.z, R.a.w, R.b.x, R.b.y, R.b.z, R.b.w,
                   R.c.x, R.c.y, R.c.z, R.c.w};
    if (edgew) {
        if (le) { w[0] = R.c.x; w[1] = R.b.w; w[2] = R.b.z; w[3] = R.b.y; }   // reflect left
        if (re) { w[8] = R.b.z; w[9] = R.b.y; w[10] = R.b.x; w[11] = R.a.w; } // reflect right
    }
    R8 h;
    #pragma unroll
    for (int j = 0; j < 8; ++j)
        h.v[j] = GW0 * (w[j] + w[j + 4]) + GW1 * (w[j + 1] + w[j + 3]) + GW2 * w[j + 2];
    return h;
}

// vertical gaussian -> blur row (8-wide), x-clamp fixups for sobel replicate pad
__device__ __forceinline__ R8 vg(const R8& a, const R8& b, const R8& c, const R8& d, const R8& e_,
                                 bool edgew, bool le, bool re) {
    R8 o;
    #pragma unroll
    for (int j = 0; j < 8; ++j)
        o.v[j] = GW0 * (a.v[j] + e_.v[j]) + GW1 * (b.v[j] + d.v[j]) + GW2 * c.v[j];
    if (edgew) {
        if (le) { o.v[0] = o.v[2]; o.v[1] = o.v[2]; }
        if (re) { o.v[6] = o.v[5]; o.v[7] = o.v[5]; }
    }
    return o;
}

// first sobel: 8-wide blur rows -> 6-wide gx,gy (x = xb-1 .. xb+4), x-clamp dup on edges
__device__ __forceinline__ void sobel(const R8& u, const R8& m, const R8& d, R6& ox, R6& oy,
                                      bool edgew, bool le, bool re) {
    #pragma unroll
    for (int j = 0; j < 6; ++j) {
        ox.v[j] = ((u.v[j+2] - u.v[j]) + 2.f*(m.v[j+2] - m.v[j]) + (d.v[j+2] - d.v[j])) * 0.125f;
        oy.v[j] = ((d.v[j] - u.v[j]) + 2.f*(d.v[j+1] - u.v[j+1]) + (d.v[j+2] - u.v[j+2])) * 0.125f;
    }
    if (edgew) {
        if (le) { ox.v[0] = ox.v[1]; oy.v[0] = oy.v[1]; }
        if (re) { ox.v[5] = ox.v[4]; oy.v[5] = oy.v[4]; }
    }
}

// exp row from a prefetched Raw; zrow -> zeros (row outside image); edge cols zeroed
__device__ __forceinline__ R8 erow_from(const Raw& R, bool zrow, bool edgew, bool le, bool re) {
    R8 o;
    if (zrow) {
        #pragma unroll
        for (int j = 0; j < 8; ++j) o.v[j] = 0.f;
        return o;
    }
    float w[8] = {R.a.z, R.a.w, R.b.x, R.b.y, R.b.z, R.b.w, R.c.x, R.c.y};
    #pragma unroll
    for (int j = 0; j < 8; ++j) o.v[j] = __expf(w[j] * 10.f);
    if (edgew) {
        if (le) { o.v[0] = 0.f; o.v[1] = 0.f; }
        if (re) { o.v[6] = 0.f; o.v[7] = 0.f; }
    }
    return o;
}

__global__ __launch_bounds__(256) void steal_main(const float* __restrict__ pred,
                                                  const float* __restrict__ lab,
                                                  unsigned int* __restrict__ counter,
                                                  float* __restrict__ acc,
                                                  float* __restrict__ out) {
    __shared__ float s_red[4];
    __shared__ int s_last;
    __shared__ double sd[256];
    const int lane = threadIdx.x & 63;
    const int wid  = (blockIdx.x << 2) + (threadIdx.x >> 6);   // 0..2047
    const int sx = wid & 7;
    const int y0 = (wid >> 3) * T;
    const int xb = sx * 256 + lane * 4;
    const bool edgew = (sx == 0) || (sx == 7);                 // wave-uniform
    const bool le = (sx == 0) && (lane == 0);
    const bool re = (sx == 7) && (lane == 63);

    const float T1f = 0.41421356237309503f;   // tan(pi/8)
    const float T3f = 2.41421356237309510f;   // tan(3pi/8)

    // ---------------- prime label pipeline ----------------
    R8 H0, H1, H2, H3, b0, b1;
    R6 gx0, gy0, gx1, gy1;
    {
        R8 A0 = make_h(load_row3(lab, reflect_row(y0 - 4), xb), edgew, le, re);
        R8 A1 = make_h(load_row3(lab, reflect_row(y0 - 3), xb), edgew, le, re);
        R8 A2 = make_h(load_row3(lab, reflect_row(y0 - 2), xb), edgew, le, re);
        R8 A3 = make_h(load_row3(lab, reflect_row(y0 - 1), xb), edgew, le, re);
        H0 = make_h(load_row3(lab, y0 + 0, xb), edgew, le, re);
        H1 = make_h(load_row3(lab, y0 + 1, xb), edgew, le, re);
        H2 = make_h(load_row3(lab, y0 + 2, xb), edgew, le, re);
        H3 = make_h(load_row3(lab, y0 + 3, xb), edgew, le, re);
        R8 bm2 = vg(A0, A1, A2, A3, H0, edgew, le, re);   // blur[y0-2]
        R8 bm1 = vg(A1, A2, A3, H0, H1, edgew, le, re);   // blur[y0-1]
        b0  = vg(A2, A3, H0, H1, H2, edgew, le, re);      // blur[y0]
        b1  = vg(A3, H0, H1, H2, H3, edgew, le, re);      // blur[y0+1]
        if (y0 > 0) {
            sobel(bm2, bm1, b0, gx0, gy0, edgew, le, re); // gxgy[y0-1]
            sobel(bm1, b0,  b1, gx1, gy1, edgew, le, re); // gxgy[y0]
        } else {
            sobel(b0, b0, b1, gx1, gy1, edgew, le, re);   // gxgy[0] (clamp dup)
            gx0 = gx1; gy0 = gy1;
        }
    }

    // ---------------- prime e window rows y0-2 .. y0+1 ----------------
    R8 e0 = erow_from(load_row3(pred, max(y0 - 2, 0), xb), (y0 - 2 < 0), edgew, le, re);
    R8 e1 = erow_from(load_row3(pred, max(y0 - 1, 0), xb), (y0 - 1 < 0), edgew, le, re);
    R8 e2 = erow_from(load_row3(pred, y0 + 0, xb), false, edgew, le, re);
    R8 e3 = erow_from(load_row3(pred, y0 + 1, xb), false, edgew, le, re);

    // ---------------- depth-2 prefetch: static slots for rows i and i+1 ----------------
    Raw LA0 = load_row3(lab, reflect_row(y0 + 4), xb);     // lab for row i   (h row y+4)
    Raw PA0 = load_row3(pred, min(y0 + 2, HH - 1), xb);    // pred for row i  (e row y+2)
    Raw LA1 = load_row3(lab, reflect_row(y0 + 5), xb);     // lab for row i+1
    Raw PA1 = load_row3(pred, min(y0 + 3, HH - 1), xb);    // pred for row i+1

    float lsum = 0.f;

    // one output row: consume slotL/slotP, immediately reissue them for row y+2
    auto process_row = [&](int y, Raw& slotL, Raw& slotP) {
        R8 bn;                                            // blur[y+2]
        if (y + 2 < HH) {
            R8 hn = make_h(slotL, edgew, le, re);
            bn = vg(H0, H1, H2, H3, hn, edgew, le, re);
            H0 = H1; H1 = H2; H2 = H3; H3 = hn;
        } else bn = b1;                                   // dup blur[H-1]

        R8 en = erow_from(slotP, (y + 2 >= HH), edgew, le, re);     // e[y+2]

        // reissue this slot for row y+2 (consumed ~2 row-bodies later)
        slotL = load_row3(lab, reflect_row(y + 6), xb);
        slotP = load_row3(pred, min(y + 4, HH - 1), xb);

        R6 gxn, gyn;                                      // gxgy[y+1]
        if (y + 1 < HH) sobel(b0, b1, bn, gxn, gyn, edgew, le, re);
        else { gxn = gx1; gyn = gy1; }

        #pragma unroll
        for (int k = 0; k < 4; ++k) {
            float gxx = ((gx0.v[k+2]-gx0.v[k]) + 2.f*(gx1.v[k+2]-gx1.v[k]) +
                         (gxn.v[k+2]-gxn.v[k])) * 0.125f;
            float gxy = ((gy0.v[k+2]-gy0.v[k]) + 2.f*(gy1.v[k+2]-gy1.v[k]) +
                         (gyn.v[k+2]-gyn.v[k])) * 0.125f;
            float gyy = ((gyn.v[k]-gy0.v[k]) + 2.f*(gyn.v[k+1]-gy0.v[k+1]) +
                         (gyn.v[k+2]-gy0.v[k+2])) * 0.125f;
            float sg = -(gxy + 1e-6f);
            float sgn = (sg > 0.f) ? 1.f : ((sg < 0.f) ? -1.f : 0.f);
            float rt = gyy * sgn * __builtin_amdgcn_rcpf(gxx + 1e-6f);

            float hs  = e2.v[k] + e2.v[k+1] + e2.v[k+2] + e2.v[k+3] + e2.v[k+4];
            float vs  = e0.v[k+2] + e1.v[k+2] + e2.v[k+2] + e3.v[k+2] + en.v[k+2];
            float dls = e0.v[k]   + e1.v[k+1] + e2.v[k+2] + e3.v[k+3] + en.v[k+4];
            float dcs = e0.v[k+4] + e1.v[k+3] + e2.v[k+2] + e3.v[k+1] + en.v[k];

            bool isH = (rt >= -T1f) && (rt < T1f);
            bool isL = (rt >=  T1f) && (rt < T3f);
            bool isC = (rt >= -T3f) && (rt < -T1f);
            bool has = isH || isL || isC || (rt >= T3f) || (rt < -T3f);  // false only for NaN
            float resp = isH ? hs : (isL ? dls : (isC ? dcs : vs));
            float lv = __logf(e2.v[k + 2]) - __logf(resp + 1e-6f);       // log(exp(pc*10)) = pc*10
            lsum += has ? lv : 0.f;
        }

        // rotate windows
        b0 = b1; b1 = bn;
        gx0 = gx1; gx1 = gxn; gy0 = gy1; gy1 = gyn;
        e0 = e1; e1 = e2; e2 = e3; e3 = en;
    };

    // rolled loop, 2 rows per iteration, static slot names
    for (int i = 0; i < T; i += 2) {
        process_row(y0 + i,     LA0, PA0);
        process_row(y0 + i + 1, LA1, PA1);
    }

    // ---------------- block reduction (wave = 64) ----------------
    float v = lsum;
    #pragma unroll
    for (int off = 32; off; off >>= 1) v += __shfl_down(v, off, 64);
    if ((threadIdx.x & 63) == 0) s_red[threadIdx.x >> 6] = v;
    __syncthreads();
    if (threadIdx.x == 0) {
        acc[blockIdx.x] = s_red[0] + s_red[1] + s_red[2] + s_red[3];
        __threadfence();                                   // publish partial device-wide
        unsigned int t = atomicAdd(counter, 1u);
        s_last = (t == (unsigned int)(gridDim.x - 1)) ? 1 : 0;
    }
    __syncthreads();

    // ---------------- last block: deterministic fixed-order finalize ----------------
    if (s_last) {
        __threadfence();                                   // acquire all partials
        const volatile float* vacc = (const volatile float*)acc;
        double a = 0.0;
        for (int i = threadIdx.x; i < NBLK; i += 256) a += (double)vacc[i];
        sd[threadIdx.x] = a;
        __syncthreads();
        for (int s = 128; s > 0; s >>= 1) {
            if (threadIdx.x < s) sd[threadIdx.x] += sd[threadIdx.x + s];
            __syncthreads();
        }
        if (threadIdx.x == 0) out[0] = (float)(-sd[0] / 4194304.0);
    }
}

extern "C" void kernel_launch(void* const* d_in, const int* in_sizes, int n_in,
                              void* d_out, int out_size, void* d_ws, size_t ws_size,
                              hipStream_t stream) {
    const float* pred = (const float*)d_in[0];   // (1,1,2048,2048) f32
    const float* lab  = (const float*)d_in[1];   // (1,2048,2048) f32
    float* out = (float*)d_out;                  // scalar f32

    unsigned int* counter = (unsigned int*)d_ws;                 // 4 B ticket counter
    float* acc = (float*)((char*)d_ws + 256);                    // 512 block partials

    hipMemsetAsync(d_ws, 0, 4, stream);          // reset ticket each call (capture-safe)
    steal_main<<<NBLK, 256, 0, stream>>>(pred, lab, counter, acc, out);
}

// Round 16
// 32.648 us; speedup vs baseline: 1.5426x; 1.5426x over previous
//
#include <hip/hip_runtime.h>
#include <math.h>

#define HH 2048
#define WW 2048
#define T 8

// Gaussian sigma=2, 5 taps, normalized
#define GW0 0.15246914402033867f
#define GW1 0.22184129554377693f
#define GW2 0.25137912086578894f

typedef float f4 __attribute__((ext_vector_type(4)));

struct R8 { float v[8]; };
struct R6 { float v[6]; };
struct Raw { f4 a, b, c; };
struct Raw2 { f4 a, b; };          // 8-float window xb-2 .. xb+5 (2 overlapping f4)

__device__ __forceinline__ int reflect_row(int vr) {
    return vr < 0 ? -vr : (vr >= HH ? 2 * HH - 2 - vr : vr);
}

__device__ __forceinline__ Raw load_row3(const float* __restrict__ p, int r, int xb) {
    const float* row = p + (size_t)r * WW;
    Raw o;
    o.a = *(const f4*)(row + max(xb - 4, 0));
    o.b = *(const f4*)(row + xb);
    o.c = *(const f4*)(row + min(xb + 4, WW - 4));
    return o;
}

// pred window loader: 2 f4 covering x = xb-2 .. xb+5 (edge lanes clamp; the
// clamped-garbage slots are exactly the ones zeroed by the le/re fixups below)
__device__ __forceinline__ Raw2 load_row2(const float* __restrict__ p, int r, int xb) {
    const float* row = p + (size_t)r * WW;
    Raw2 o;
    o.a = *(const f4*)(row + max(xb - 2, 0));            // xb-2 .. xb+1 (8B aligned)
    o.b = *(const f4*)(row + min(xb + 2, WW - 4));       // xb+2 .. xb+5
    return o;
}

// horizontal gaussian from raw lab row; output covers x = xb-2 .. xb+5
__device__ __forceinline__ R8 make_h(const Raw& R, bool edgew, bool le, bool re) {
    float w[12] = {R.a.x, R.a.y, R.a.z, R.a.w, R.b.x, R.b.y, R.b.z, R.b.w,
                   R.c.x, R.c.y, R.c.z, R.c.w};
    if (edgew) {
        if (le) { w[0] = R.c.x; w[1] = R.b.w; w[2] = R.b.z; w[3] = R.b.y; }   // reflect left
        if (re) { w[8] = R.b.z; w[9] = R.b.y; w[10] = R.b.x; w[11] = R.a.w; } // reflect right
    }
    R8 h;
    #pragma unroll
    for (int j = 0; j < 8; ++j)
        h.v[j] = GW0 * (w[j] + w[j + 4]) + GW1 * (w[j + 1] + w[j + 3]) + GW2 * w[j + 2];
    return h;
}

// vertical gaussian -> blur row (8-wide), x-clamp fixups for sobel replicate pad
__device__ __forceinline__ R8 vg(const R8& a, const R8& b, const R8& c, const R8& d, const R8& e_,
                                 bool edgew, bool le, bool re) {
    R8 o;
    #pragma unroll
    for (int j = 0; j < 8; ++j)
        o.v[j] = GW0 * (a.v[j] + e_.v[j]) + GW1 * (b.v[j] + d.v[j]) + GW2 * c.v[j];
    if (edgew) {
        if (le) { o.v[0] = o.v[2]; o.v[1] = o.v[2]; }
        if (re) { o.v[6] = o.v[5]; o.v[7] = o.v[5]; }
    }
    return o;
}

// first sobel: 8-wide blur rows -> 6-wide gx,gy (x = xb-1 .. xb+4), x-clamp dup on edges
__device__ __forceinline__ void sobel(const R8& u, const R8& m, const R8& d, R6& ox, R6& oy,
                                      bool edgew, bool le, bool re) {
    #pragma unroll
    for (int j = 0; j < 6; ++j) {
        ox.v[j] = ((u.v[j+2] - u.v[j]) + 2.f*(m.v[j+2] - m.v[j]) + (d.v[j+2] - d.v[j])) * 0.125f;
        oy.v[j] = ((d.v[j] - u.v[j]) + 2.f*(d.v[j+1] - u.v[j+1]) + (d.v[j+2] - u.v[j+2])) * 0.125f;
    }
    if (edgew) {
        if (le) { ox.v[0] = ox.v[1]; oy.v[0] = oy.v[1]; }
        if (re) { ox.v[5] = ox.v[4]; oy.v[5] = oy.v[4]; }
    }
}

// exp row from a prefetched Raw2; zrow -> zeros; edge cols zeroed (covers clamp garbage)
__device__ __forceinline__ R8 erow_from(const Raw2& R, bool zrow, bool edgew, bool le, bool re) {
    R8 o;
    if (zrow) {
        #pragma unroll
        for (int j = 0; j < 8; ++j) o.v[j] = 0.f;
        return o;
    }
    float w[8] = {R.a.x, R.a.y, R.a.z, R.a.w, R.b.x, R.b.y, R.b.z, R.b.w};
    #pragma unroll
    for (int j = 0; j < 8; ++j) o.v[j] = __expf(w[j] * 10.f);
    if (edgew) {
        if (le) { o.v[0] = 0.f; o.v[1] = 0.f; }
        if (re) { o.v[6] = 0.f; o.v[7] = 0.f; }
    }
    return o;
}

__global__ __launch_bounds__(256) void steal_main(const float* __restrict__ pred,
                                                  const float* __restrict__ lab,
                                                  float* __restrict__ acc) {
    __shared__ float s_red[4];
    const int lane = threadIdx.x & 63;
    const int wid  = (blockIdx.x << 2) + (threadIdx.x >> 6);   // 0..2047
    const int sx = wid & 7;
    const int y0 = (wid >> 3) * T;
    const int xb = sx * 256 + lane * 4;
    const bool edgew = (sx == 0) || (sx == 7);                 // wave-uniform
    const bool le = (sx == 0) && (lane == 0);
    const bool re = (sx == 7) && (lane == 63);

    const float T1f = 0.41421356237309503f;   // tan(pi/8)
    const float T3f = 2.41421356237309510f;   // tan(3pi/8)

    // ---------------- prime label pipeline ----------------
    R8 H0, H1, H2, H3, b0, b1;
    R6 gx0, gy0, gx1, gy1;
    {
        R8 A0 = make_h(load_row3(lab, reflect_row(y0 - 4), xb), edgew, le, re);
        R8 A1 = make_h(load_row3(lab, reflect_row(y0 - 3), xb), edgew, le, re);
        R8 A2 = make_h(load_row3(lab, reflect_row(y0 - 2), xb), edgew, le, re);
        R8 A3 = make_h(load_row3(lab, reflect_row(y0 - 1), xb), edgew, le, re);
        H0 = make_h(load_row3(lab, y0 + 0, xb), edgew, le, re);
        H1 = make_h(load_row3(lab, y0 + 1, xb), edgew, le, re);
        H2 = make_h(load_row3(lab, y0 + 2, xb), edgew, le, re);
        H3 = make_h(load_row3(lab, y0 + 3, xb), edgew, le, re);
        R8 bm2 = vg(A0, A1, A2, A3, H0, edgew, le, re);   // blur[y0-2]
        R8 bm1 = vg(A1, A2, A3, H0, H1, edgew, le, re);   // blur[y0-1]
        b0  = vg(A2, A3, H0, H1, H2, edgew, le, re);      // blur[y0]
        b1  = vg(A3, H0, H1, H2, H3, edgew, le, re);      // blur[y0+1]
        if (y0 > 0) {
            sobel(bm2, bm1, b0, gx0, gy0, edgew, le, re); // gxgy[y0-1]
            sobel(bm1, b0,  b1, gx1, gy1, edgew, le, re); // gxgy[y0]
        } else {
            sobel(b0, b0, b1, gx1, gy1, edgew, le, re);   // gxgy[0] (clamp dup)
            gx0 = gx1; gy0 = gy1;
        }
    }

    // ---------------- prime e window rows y0-2 .. y0+1 ----------------
    R8 e0 = erow_from(load_row2(pred, max(y0 - 2, 0), xb), (y0 - 2 < 0), edgew, le, re);
    R8 e1 = erow_from(load_row2(pred, max(y0 - 1, 0), xb), (y0 - 1 < 0), edgew, le, re);
    R8 e2 = erow_from(load_row2(pred, y0 + 0, xb), false, edgew, le, re);
    R8 e3 = erow_from(load_row2(pred, y0 + 1, xb), false, edgew, le, re);

    // ---------------- depth-2 prefetch: static slots for rows i and i+1 ----------------
    Raw  LA0 = load_row3(lab, reflect_row(y0 + 4), xb);    // lab for row i   (h row y+4)
    Raw2 PA0 = load_row2(pred, min(y0 + 2, HH - 1), xb);   // pred for row i  (e row y+2)
    Raw  LA1 = load_row3(lab, reflect_row(y0 + 5), xb);    // lab for row i+1
    Raw2 PA1 = load_row2(pred, min(y0 + 3, HH - 1), xb);   // pred for row i+1

    float lsum = 0.f;

    // one output row: consume slotL/slotP, immediately reissue them for row y+2
    auto process_row = [&](int y, Raw& slotL, Raw2& slotP) {
        R8 bn;                                            // blur[y+2]
        if (y + 2 < HH) {
            R8 hn = make_h(slotL, edgew, le, re);
            bn = vg(H0, H1, H2, H3, hn, edgew, le, re);
            H0 = H1; H1 = H2; H2 = H3; H3 = hn;
        } else bn = b1;                                   // dup blur[H-1]

        R8 en = erow_from(slotP, (y + 2 >= HH), edgew, le, re);     // e[y+2]

        // reissue this slot for row y+2 (consumed ~2 row-bodies later)
        slotL = load_row3(lab, reflect_row(y + 6), xb);
        slotP = load_row2(pred, min(y + 4, HH - 1), xb);

        R6 gxn, gyn;                                      // gxgy[y+1]
        if (y + 1 < HH) sobel(b0, b1, bn, gxn, gyn, edgew, le, re);
        else { gxn = gx1; gyn = gy1; }

        #pragma unroll
        for (int k = 0; k < 4; ++k) {
            float gxx = ((gx0.v[k+2]-gx0.v[k]) + 2.f*(gx1.v[k+2]-gx1.v[k]) +
                         (gxn.v[k+2]-gxn.v[k])) * 0.125f;
            float gxy = ((gy0.v[k+2]-gy0.v[k]) + 2.f*(gy1.v[k+2]-gy1.v[k]) +
                         (gyn.v[k+2]-gyn.v[k])) * 0.125f;
            float gyy = ((gyn.v[k]-gy0.v[k]) + 2.f*(gyn.v[k+1]-gy0.v[k+1]) +
                         (gyn.v[k+2]-gy0.v[k+2])) * 0.125f;
            float sg = -(gxy + 1e-6f);
            float sgn = (sg > 0.f) ? 1.f : ((sg < 0.f) ? -1.f : 0.f);
            float rt = gyy * sgn * __builtin_amdgcn_rcpf(gxx + 1e-6f);

            float hs  = e2.v[k] + e2.v[k+1] + e2.v[k+2] + e2.v[k+3] + e2.v[k+4];
            float vs  = e0.v[k+2] + e1.v[k+2] + e2.v[k+2] + e3.v[k+2] + en.v[k+2];
            float dls = e0.v[k]   + e1.v[k+1] + e2.v[k+2] + e3.v[k+3] + en.v[k+4];
            float dcs = e0.v[k+4] + e1.v[k+3] + e2.v[k+2] + e3.v[k+1] + en.v[k];

            bool isH = (rt >= -T1f) && (rt < T1f);
            bool isL = (rt >=  T1f) && (rt < T3f);
            bool isC = (rt >= -T3f) && (rt < -T1f);
            bool has = isH || isL || isC || (rt >= T3f) || (rt < -T3f);  // false only for NaN
            float resp = isH ? hs : (isL ? dls : (isC ? dcs : vs));
            float lv = __logf(e2.v[k + 2]) - __logf(resp + 1e-6f);       // log(exp(pc*10)) = pc*10
            lsum += has ? lv : 0.f;
        }

        // rotate windows
        b0 = b1; b1 = bn;
        gx0 = gx1; gx1 = gxn; gy0 = gy1; gy1 = gyn;
        e0 = e1; e1 = e2; e2 = e3; e3 = en;
    };

    // rolled loop, 2 rows per iteration, static slot names
    for (int i = 0; i < T; i += 2) {
        process_row(y0 + i,     LA0, PA0);
        process_row(y0 + i + 1, LA1, PA1);
    }

    // ---------------- block reduction (wave = 64) ----------------
    float v = lsum;
    #pragma unroll
    for (int off = 32; off; off >>= 1) v += __shfl_down(v, off, 64);
    if ((threadIdx.x & 63) == 0) s_red[threadIdx.x >> 6] = v;
    __syncthreads();
    if (threadIdx.x == 0) {
        acc[blockIdx.x] = s_red[0] + s_red[1] + s_red[2] + s_red[3];
    }
}

__global__ __launch_bounds__(256) void steal_finalize(const float* __restrict__ acc,
                                                      float* __restrict__ out, int n) {
    __shared__ double sd[256];
    double a = 0.0;
    int n4 = n >> 2;
    for (int i = threadIdx.x; i < n4; i += 256) {
        f4 v = *(const f4*)(acc + i * 4);
        a += (double)v.x + (double)v.y + (double)v.z + (double)v.w;
    }
    for (int i = (n4 << 2) + threadIdx.x; i < n; i += 256) a += (double)acc[i];
    sd[threadIdx.x] = a;
    __syncthreads();
    for (int s = 128; s > 0; s >>= 1) {
        if (threadIdx.x < s) sd[threadIdx.x] += sd[threadIdx.x + s];
        __syncthreads();
    }
    if (threadIdx.x == 0) out[0] = (float)(-sd[0] / 4194304.0);
}

extern "C" void kernel_launch(void* const* d_in, const int* in_sizes, int n_in,
                              void* d_out, int out_size, void* d_ws, size_t ws_size,
                              hipStream_t stream) {
    const float* pred = (const float*)d_in[0];   // (1,1,2048,2048) f32
    const float* lab  = (const float*)d_in[1];   // (1,2048,2048) f32
    float* out = (float*)d_out;                  // scalar f32
    float* ws  = (float*)d_ws;

    const int nwaves = 8 * (HH / T);             // 2048 wave-jobs
    const int nblocks = nwaves / 4;              // 512 blocks x 256 threads

    steal_main<<<nblocks, 256, 0, stream>>>(pred, lab, ws);
    steal_finalize<<<1, 256, 0, stream>>>(ws, out, nblocks);
}

// Round 17
// 31.140 us; speedup vs baseline: 1.6174x; 1.0484x over previous
//
#include <hip/hip_runtime.h>
#include <math.h>

#define HH 2048
#define WW 2048
#define T 8

// Gaussian sigma=2, 5 taps, normalized
#define GW0 0.15246914402033867f
#define GW1 0.22184129554377693f
#define GW2 0.25137912086578894f

typedef float f4 __attribute__((ext_vector_type(4)));

struct R8 { float v[8]; };
struct R6 { float v[6]; };
struct Raw { f4 a, b, c; };
struct Raw2 { f4 a, b; };          // 8-float window xb-2 .. xb+5 (2 overlapping f4)

__device__ __forceinline__ int reflect_row(int vr) {
    return vr < 0 ? -vr : (vr >= HH ? 2 * HH - 2 - vr : vr);
}

__device__ __forceinline__ Raw load_row3(const float* __restrict__ p, int r, int xb) {
    const float* row = p + (size_t)r * WW;
    Raw o;
    o.a = *(const f4*)(row + max(xb - 4, 0));
    o.b = *(const f4*)(row + xb);
    o.c = *(const f4*)(row + min(xb + 4, WW - 4));
    return o;
}

// pred window loader: 2 f4 covering x = xb-2 .. xb+5 (edge lanes clamp; the
// clamped-garbage slots are exactly the ones zeroed by the le/re fixups below)
__device__ __forceinline__ Raw2 load_row2(const float* __restrict__ p, int r, int xb) {
    const float* row = p + (size_t)r * WW;
    Raw2 o;
    o.a = *(const f4*)(row + max(xb - 2, 0));            // xb-2 .. xb+1 (8B aligned)
    o.b = *(const f4*)(row + min(xb + 2, WW - 4));       // xb+2 .. xb+5
    return o;
}

// horizontal gaussian from raw lab row; output covers x = xb-2 .. xb+5
__device__ __forceinline__ R8 make_h(const Raw& R, bool edgew, bool le, bool re) {
    float w[12] = {R.a.x, R.a.y, R.a.z, R.a.w, R.b.x, R.b.y, R.b.z, R.b.w,
                   R.c.x, R.c.y, R.c.z, R.c.w};
    if (edgew) {
        if (le) { w[0] = R.c.x; w[1] = R.b.w; w[2] = R.b.z; w[3] = R.b.y; }   // reflect left
        if (re) { w[8] = R.b.z; w[9] = R.b.y; w[10] = R.b.x; w[11] = R.a.w; } // reflect right
    }
    R8 h;
    #pragma unroll
    for (int j = 0; j < 8; ++j)
        h.v[j] = GW0 * (w[j] + w[j + 4]) + GW1 * (w[j + 1] + w[j + 3]) + GW2 * w[j + 2];
    return h;
}

// vertical gaussian -> blur row (8-wide), x-clamp fixups for sobel replicate pad
__device__ __forceinline__ R8 vg(const R8& a, const R8& b, const R8& c, const R8& d, const R8& e_,
                                 bool edgew, bool le, bool re) {
    R8 o;
    #pragma unroll
    for (int j = 0; j < 8; ++j)
        o.v[j] = GW0 * (a.v[j] + e_.v[j]) + GW1 * (b.v[j] + d.v[j]) + GW2 * c.v[j];
    if (edgew) {
        if (le) { o.v[0] = o.v[2]; o.v[1] = o.v[2]; }
        if (re) { o.v[6] = o.v[5]; o.v[7] = o.v[5]; }
    }
    return o;
}

// first sobel: 8-wide blur rows -> 6-wide gx,gy (x = xb-1 .. xb+4), x-clamp dup on edges
__device__ __forceinline__ void sobel(const R8& u, const R8& m, const R8& d, R6& ox, R6& oy,
                                      bool edgew, bool le, bool re) {
    #pragma unroll
    for (int j = 0; j < 6; ++j) {
        ox.v[j] = ((u.v[j+2] - u.v[j]) + 2.f*(m.v[j+2] - m.v[j]) + (d.v[j+2] - d.v[j])) * 0.125f;
        oy.v[j] = ((d.v[j] - u.v[j]) + 2.f*(d.v[j+1] - u.v[j+1]) + (d.v[j+2] - u.v[j+2])) * 0.125f;
    }
    if (edgew) {
        if (le) { ox.v[0] = ox.v[1]; oy.v[0] = oy.v[1]; }
        if (re) { ox.v[5] = ox.v[4]; oy.v[5] = oy.v[4]; }
    }
}

// exp row from a prefetched Raw2; zrow -> zeros; edge cols zeroed (covers clamp garbage)
__device__ __forceinline__ R8 erow_from(const Raw2& R, bool zrow, bool edgew, bool le, bool re) {
    R8 o;
    if (zrow) {
        #pragma unroll
        for (int j = 0; j < 8; ++j) o.v[j] = 0.f;
        return o;
    }
    float w[8] = {R.a.x, R.a.y, R.a.z, R.a.w, R.b.x, R.b.y, R.b.z, R.b.w};
    #pragma unroll
    for (int j = 0; j < 8; ++j) o.v[j] = __expf(w[j] * 10.f);
    if (edgew) {
        if (le) { o.v[0] = 0.f; o.v[1] = 0.f; }
        if (re) { o.v[6] = 0.f; o.v[7] = 0.f; }
    }
    return o;
}

__global__ __launch_bounds__(256) void steal_main(const float* __restrict__ pred,
                                                  const float* __restrict__ lab,
                                                  float* __restrict__ acc) {
    __shared__ float s_red[4];
    const int lane = threadIdx.x & 63;

    // XCD-aware swizzle (bijective: 512 blocks, 8 XCDs): XCD k owns the contiguous
    // row-group band rg in [32k, 32k+32) across all 8 column strips, so vertical-halo
    // re-touches hit that XCD's L2 instead of L3.
    const int xcd   = blockIdx.x & 7;
    const int idx   = blockIdx.x >> 3;                       // 0..63
    const int local = (idx << 2) + (threadIdx.x >> 6);       // 0..255 within XCD
    const int sx = local & 7;
    const int rg = (xcd << 5) + (local >> 3);                // 0..255
    const int y0 = rg * T;
    const int xb = sx * 256 + lane * 4;
    const bool edgew = (sx == 0) || (sx == 7);               // wave-uniform
    const bool le = (sx == 0) && (lane == 0);
    const bool re = (sx == 7) && (lane == 63);

    const float T1f = 0.41421356237309503f;   // tan(pi/8)
    const float T3f = 2.41421356237309510f;   // tan(3pi/8)

    // ---------------- prime label pipeline ----------------
    R8 H0, H1, H2, H3, b0, b1;
    R6 gx0, gy0, gx1, gy1;
    {
        R8 A0 = make_h(load_row3(lab, reflect_row(y0 - 4), xb), edgew, le, re);
        R8 A1 = make_h(load_row3(lab, reflect_row(y0 - 3), xb), edgew, le, re);
        R8 A2 = make_h(load_row3(lab, reflect_row(y0 - 2), xb), edgew, le, re);
        R8 A3 = make_h(load_row3(lab, reflect_row(y0 - 1), xb), edgew, le, re);
        H0 = make_h(load_row3(lab, y0 + 0, xb), edgew, le, re);
        H1 = make_h(load_row3(lab, y0 + 1, xb), edgew, le, re);
        H2 = make_h(load_row3(lab, y0 + 2, xb), edgew, le, re);
        H3 = make_h(load_row3(lab, y0 + 3, xb), edgew, le, re);
        R8 bm2 = vg(A0, A1, A2, A3, H0, edgew, le, re);   // blur[y0-2]
        R8 bm1 = vg(A1, A2, A3, H0, H1, edgew, le, re);   // blur[y0-1]
        b0  = vg(A2, A3, H0, H1, H2, edgew, le, re);      // blur[y0]
        b1  = vg(A3, H0, H1, H2, H3, edgew, le, re);      // blur[y0+1]
        if (y0 > 0) {
            sobel(bm2, bm1, b0, gx0, gy0, edgew, le, re); // gxgy[y0-1]
            sobel(bm1, b0,  b1, gx1, gy1, edgew, le, re); // gxgy[y0]
        } else {
            sobel(b0, b0, b1, gx1, gy1, edgew, le, re);   // gxgy[0] (clamp dup)
            gx0 = gx1; gy0 = gy1;
        }
    }

    // ---------------- prime e window rows y0-2 .. y0+1 ----------------
    R8 e0 = erow_from(load_row2(pred, max(y0 - 2, 0), xb), (y0 - 2 < 0), edgew, le, re);
    R8 e1 = erow_from(load_row2(pred, max(y0 - 1, 0), xb), (y0 - 1 < 0), edgew, le, re);
    R8 e2 = erow_from(load_row2(pred, y0 + 0, xb), false, edgew, le, re);
    R8 e3 = erow_from(load_row2(pred, y0 + 1, xb), false, edgew, le, re);

    // ---------------- depth-2 prefetch: static slots for rows i and i+1 ----------------
    Raw  LA0 = load_row3(lab, reflect_row(y0 + 4), xb);    // lab for row i   (h row y+4)
    Raw2 PA0 = load_row2(pred, min(y0 + 2, HH - 1), xb);   // pred for row i  (e row y+2)
    Raw  LA1 = load_row3(lab, reflect_row(y0 + 5), xb);    // lab for row i+1
    Raw2 PA1 = load_row2(pred, min(y0 + 3, HH - 1), xb);   // pred for row i+1

    float lsum = 0.f;

    // one output row: consume slotL/slotP, immediately reissue them for row y+2
    auto process_row = [&](int y, Raw& slotL, Raw2& slotP) {
        R8 bn;                                            // blur[y+2]
        if (y + 2 < HH) {
            R8 hn = make_h(slotL, edgew, le, re);
            bn = vg(H0, H1, H2, H3, hn, edgew, le, re);
            H0 = H1; H1 = H2; H2 = H3; H3 = hn;
        } else bn = b1;                                   // dup blur[H-1]

        R8 en = erow_from(slotP, (y + 2 >= HH), edgew, le, re);     // e[y+2]

        // reissue this slot for row y+2 (consumed ~2 row-bodies later)
        slotL = load_row3(lab, reflect_row(y + 6), xb);
        slotP = load_row2(pred, min(y + 4, HH - 1), xb);

        R6 gxn, gyn;                                      // gxgy[y+1]
        if (y + 1 < HH) sobel(b0, b1, bn, gxn, gyn, edgew, le, re);
        else { gxn = gx1; gyn = gy1; }

        #pragma unroll
        for (int k = 0; k < 4; ++k) {
            float gxx = ((gx0.v[k+2]-gx0.v[k]) + 2.f*(gx1.v[k+2]-gx1.v[k]) +
                         (gxn.v[k+2]-gxn.v[k])) * 0.125f;
            float gxy = ((gy0.v[k+2]-gy0.v[k]) + 2.f*(gy1.v[k+2]-gy1.v[k]) +
                         (gyn.v[k+2]-gyn.v[k])) * 0.125f;
            float gyy = ((gyn.v[k]-gy0.v[k]) + 2.f*(gyn.v[k+1]-gy0.v[k+1]) +
                         (gyn.v[k+2]-gy0.v[k+2])) * 0.125f;
            float sg = -(gxy + 1e-6f);
            float sgn = (sg > 0.f) ? 1.f : ((sg < 0.f) ? -1.f : 0.f);
            float rt = gyy * sgn * __builtin_amdgcn_rcpf(gxx + 1e-6f);

            float hs  = e2.v[k] + e2.v[k+1] + e2.v[k+2] + e2.v[k+3] + e2.v[k+4];
            float vs  = e0.v[k+2] + e1.v[k+2] + e2.v[k+2] + e3.v[k+2] + en.v[k+2];
            float dls = e0.v[k]   + e1.v[k+1] + e2.v[k+2] + e3.v[k+3] + en.v[k+4];
            float dcs = e0.v[k+4] + e1.v[k+3] + e2.v[k+2] + e3.v[k+1] + en.v[k];

            bool isH = (rt >= -T1f) && (rt < T1f);
            bool isL = (rt >=  T1f) && (rt < T3f);
            bool isC = (rt >= -T3f) && (rt < -T1f);
            bool has = isH || isL || isC || (rt >= T3f) || (rt < -T3f);  // false only for NaN
            float resp = isH ? hs : (isL ? dls : (isC ? dcs : vs));
            float lv = __logf(e2.v[k + 2]) - __logf(resp + 1e-6f);       // log(exp(pc*10)) = pc*10
            lsum += has ? lv : 0.f;
        }

        // rotate windows
        b0 = b1; b1 = bn;
        gx0 = gx1; gx1 = gxn; gy0 = gy1; gy1 = gyn;
        e0 = e1; e1 = e2; e2 = e3; e3 = en;
    };

    // rolled loop, 2 rows per iteration, static slot names
    for (int i = 0; i < T; i += 2) {
        process_row(y0 + i,     LA0, PA0);
        process_row(y0 + i + 1, LA1, PA1);
    }

    // ---------------- block reduction (wave = 64) ----------------
    float v = lsum;
    #pragma unroll
    for (int off = 32; off; off >>= 1) v += __shfl_down(v, off, 64);
    if ((threadIdx.x & 63) == 0) s_red[threadIdx.x >> 6] = v;
    __syncthreads();
    if (threadIdx.x == 0) {
        acc[blockIdx.x] = s_red[0] + s_red[1] + s_red[2] + s_red[3];
    }
}

__global__ __launch_bounds__(256) void steal_finalize(const float* __restrict__ acc,
                                                      float* __restrict__ out, int n) {
    __shared__ double sd[256];
    double a = 0.0;
    int n4 = n >> 2;
    for (int i = threadIdx.x; i < n4; i += 256) {
        f4 v = *(const f4*)(acc + i * 4);
        a += (double)v.x + (double)v.y + (double)v.z + (double)v.w;
    }
    for (int i = (n4 << 2) + threadIdx.x; i < n; i += 256) a += (double)acc[i];
    sd[threadIdx.x] = a;
    __syncthreads();
    for (int s = 128; s > 0; s >>= 1) {
        if (threadIdx.x < s) sd[threadIdx.x] += sd[threadIdx.x + s];
        __syncthreads();
    }
    if (threadIdx.x == 0) out[0] = (float)(-sd[0] / 4194304.0);
}

extern "C" void kernel_launch(void* const* d_in, const int* in_sizes, int n_in,
                              void* d_out, int out_size, void* d_ws, size_t ws_size,
                              hipStream_t stream) {
    const float* pred = (const float*)d_in[0];   // (1,1,2048,2048) f32
    const float* lab  = (const float*)d_in[1];   // (1,2048,2048) f32
    float* out = (float*)d_out;                  // scalar f32
    float* ws  = (float*)d_ws;

    const int nwaves = 8 * (HH / T);             // 2048 wave-jobs
    const int nblocks = nwaves / 4;              // 512 blocks x 256 threads

    steal_main<<<nblocks, 256, 0, stream>>>(pred, lab, ws);
    steal_finalize<<<1, 256, 0, stream>>>(ws, out, nblocks);
}